// Round 4
// baseline (5120.075 us; speedup 1.0000x reference)
//
#include <hip/hip_runtime.h>

#define NV 100000
#define ND 300
#define NH 512
#define NB 25
#define NT 600
#define NM 15000   // NB*NT
#define NG 1536    // 3*NH

typedef _Float16 v8h __attribute__((ext_vector_type(8)));
typedef _Float16 v4h __attribute__((ext_vector_type(4)));
typedef _Float16 v2h __attribute__((ext_vector_type(2)));
typedef float    v4f __attribute__((ext_vector_type(4)));
typedef unsigned long long ull;

static __device__ __forceinline__ float fsigmoid(float x) {
  return __builtin_amdgcn_rcpf(1.f + __expf(-x));
}
static __device__ __forceinline__ float ftanh(float x) {
  return 1.f - 2.f * __builtin_amdgcn_rcpf(1.f + __expf(2.f * x));
}

// ---------------- GEMM: Cxg[m][n] = emb[words[m]]·w_ih0[n] + b_ih0[n], f16 out ----
__global__ __launch_bounds__(256) void k_gemm0(
    const int* __restrict__ words, const float* __restrict__ emb,
    const float* __restrict__ Bw, const float* __restrict__ bias,
    _Float16* __restrict__ Cxg)
{
  constexpr int K = ND;
  constexpr int NKT = (K + 31) / 32;
  __shared__ _Float16 As[128][40];
  __shared__ _Float16 Bh[128][40];
  __shared__ _Float16 Bl[128][40];
  const int tid = threadIdx.x;
  const int m0 = blockIdx.x * 128, n0 = blockIdx.y * 128;
  const int w = tid >> 6, l = tid & 63;
  const int wm = w >> 1, wn = w & 1;
  const int l15 = l & 15, q = l >> 4;

  v4f accH[4][4], accL[4][4];
  for (int a = 0; a < 4; ++a)
    for (int b = 0; b < 4; ++b) {
      v4f z = {0.f, 0.f, 0.f, 0.f};
      accH[a][b] = z; accL[a][b] = z;
    }

#pragma unroll 1
  for (int kt = 0; kt < NKT; ++kt) {
    const int kb = kt * 32;
    for (int jj = 0; jj < 4; ++jj) {
      const int F = tid + 256 * jj;
      const int row = F >> 3;
      const int kl = (F & 7) * 4;
      {
        const int m = m0 + row;
        float x0 = 0.f, x1 = 0.f, x2 = 0.f, x3 = 0.f;
        if (m < NM) {
          const int word = words[m];
          const float* ap = emb + (long)word * ND + kb + kl;
          if (kb + kl + 3 < K) {
            float4 v = *(const float4*)ap;
            x0 = v.x; x1 = v.y; x2 = v.z; x3 = v.w;
          } else {
            if (kb + kl + 0 < K) x0 = ap[0];
            if (kb + kl + 1 < K) x1 = ap[1];
            if (kb + kl + 2 < K) x2 = ap[2];
            if (kb + kl + 3 < K) x3 = ap[3];
          }
        }
        v4h hv; hv[0]=(_Float16)x0; hv[1]=(_Float16)x1; hv[2]=(_Float16)x2; hv[3]=(_Float16)x3;
        *(v4h*)&As[row][kl] = hv;
      }
      {
        const int n = n0 + row;
        const float* bp = Bw + (long)n * K + kb + kl;
        float x[4] = {0.f, 0.f, 0.f, 0.f};
        if (kb + kl + 3 < K) {
          float4 v = *(const float4*)bp;
          x[0] = v.x; x[1] = v.y; x[2] = v.z; x[3] = v.w;
        } else {
          for (int c = 0; c < 4; ++c) if (kb + kl + c < K) x[c] = bp[c];
        }
        v4h bh, bl;
        for (int c = 0; c < 4; ++c) {
          _Float16 hi = (_Float16)x[c];
          bh[c] = hi;
          bl[c] = (_Float16)((x[c] - (float)hi) * 1024.f);
        }
        *(v4h*)&Bh[row][kl] = bh;
        *(v4h*)&Bl[row][kl] = bl;
      }
    }
    __syncthreads();
    v8h af[4];
    for (int mt = 0; mt < 4; ++mt) {
      const int r = wm * 64 + mt * 16 + l15;
      af[mt] = *(const v8h*)&As[r][q * 8];
    }
    for (int nt = 0; nt < 4; ++nt) {
      const int r = wn * 64 + nt * 16 + l15;
      v8h bh = *(const v8h*)&Bh[r][q * 8];
      v8h bl = *(const v8h*)&Bl[r][q * 8];
      for (int mt = 0; mt < 4; ++mt) {
        accH[mt][nt] = __builtin_amdgcn_mfma_f32_16x16x32_f16(af[mt], bh, accH[mt][nt], 0, 0, 0);
        accL[mt][nt] = __builtin_amdgcn_mfma_f32_16x16x32_f16(af[mt], bl, accL[mt][nt], 0, 0, 0);
      }
    }
    __syncthreads();
  }
  for (int nt = 0; nt < 4; ++nt) {
    const int n = n0 + wn * 64 + nt * 16 + l15;
    const float bv = bias[n];
    for (int mt = 0; mt < 4; ++mt) {
      for (int r = 0; r < 4; ++r) {
        const int m = m0 + wm * 64 + mt * 16 + q * 4 + r;
        if (m < NM) {
          const float cv = accH[mt][nt][r] + accL[mt][nt][r] * (1.f / 1024.f) + bv;
          Cxg[(long)m * NG + n] = (_Float16)cv;
        }
      }
    }
  }
}

// ---------------- fused 2-layer persistent GRU scan ----------------
// 32 blocks x 384 thr = 6 waves = (mt in 0..2) x (kh in 0..1 K-halves).
// Block owns units [u0,u0+16) of BOTH layers. W (whh0, wih1, whh1) single-f16
// in registers: per wave 16 rows x 256 K per matrix = 32 VGPR each.
// Layer-1 lags layer-0 by one iteration; xg1 = wih1·h0 on the fly (shares
// the h0 B-fragments with gh0). Exchange: 64-bit tagged stores, parity-2
// buffers, single fused 34-slot poll sweep (one IC round-trip per sweep).
__global__ __launch_bounds__(384) void k_scan2(
    const _Float16* __restrict__ xg,    // [NM][NG] f16, includes b_ih0
    const float* __restrict__ whh0,     // [NG][NH]
    const float* __restrict__ wih1,     // [NG][NH]
    const float* __restrict__ whh1,     // [NG][NH]
    const float* __restrict__ bhh0,     // [NG]
    const float* __restrict__ bih1,     // [NG]
    const float* __restrict__ bhh1,     // [NG]
    const float* __restrict__ hinit,    // [2][NB][NH]
    ull* __restrict__ H0PK,             // [2][6400] tagged h0 pairs
    ull* __restrict__ H1PK,             // [2][6400] tagged h1 pairs
    float* __restrict__ hfin0,          // d_out h0 slice
    float* __restrict__ hfin1)          // d_out h1 slice
{
  __shared__ __align__(16) _Float16 hs0[NB][520];
  __shared__ __align__(16) _Float16 hs1[NB][520];
  __shared__ float g0[2][48][28];   // gh0 partials per K-half
  __shared__ float gx[2][48][28];   // xg1 partials
  __shared__ float g1[2][48][28];   // gh1 partials
  const int tid = threadIdx.x;
  const int u0 = blockIdx.x * 16;
  const int w = tid >> 6, l = tid & 63;
  const int mt = w % 3, kh = w / 3;
  const int l15 = l & 15, q = l >> 4;

  // ---- W fragments -> registers (single f16) ----
  v8h a0[8], ax[8], a1[8];
  {
    const long base = (long)(mt * 512 + u0 + l15) * 512 + kh * 256 + q * 8;
    for (int ks = 0; ks < 8; ++ks) {
      float4 v0, v1;
      v8h h;
      v0 = *(const float4*)(whh0 + base + ks * 32);
      v1 = *(const float4*)(whh0 + base + ks * 32 + 4);
      h[0]=(_Float16)v0.x; h[1]=(_Float16)v0.y; h[2]=(_Float16)v0.z; h[3]=(_Float16)v0.w;
      h[4]=(_Float16)v1.x; h[5]=(_Float16)v1.y; h[6]=(_Float16)v1.z; h[7]=(_Float16)v1.w;
      a0[ks] = h;
      v0 = *(const float4*)(wih1 + base + ks * 32);
      v1 = *(const float4*)(wih1 + base + ks * 32 + 4);
      h[0]=(_Float16)v0.x; h[1]=(_Float16)v0.y; h[2]=(_Float16)v0.z; h[3]=(_Float16)v0.w;
      h[4]=(_Float16)v1.x; h[5]=(_Float16)v1.y; h[6]=(_Float16)v1.z; h[7]=(_Float16)v1.w;
      ax[ks] = h;
      v0 = *(const float4*)(whh1 + base + ks * 32);
      v1 = *(const float4*)(whh1 + base + ks * 32 + 4);
      h[0]=(_Float16)v0.x; h[1]=(_Float16)v0.y; h[2]=(_Float16)v0.z; h[3]=(_Float16)v0.w;
      h[4]=(_Float16)v1.x; h[5]=(_Float16)v1.y; h[6]=(_Float16)v1.z; h[7]=(_Float16)v1.w;
      a1[ks] = h;
    }
  }
  // ---- initial h stage ----
  for (int idx = tid; idx < NB * NH; idx += 384) {
    hs0[idx >> 9][idx & 511] = (_Float16)hinit[idx];
    hs1[idx >> 9][idx & 511] = (_Float16)hinit[NB * NH + idx];
  }
  __syncthreads();

  const bool ga = (tid < 200);         // (batch gb 0..24) x (gj 0..7), 2 units each
  const int gb = tid >> 3, gj = tid & 7;
  const int i0 = 2 * gj, i1 = i0 + 1;

  // exact fp32 recurrent state (thread-private: the same thread updates it)
  float h0p0 = 0.f, h0p1 = 0.f, h1p0 = 0.f, h1p1 = 0.f;
  float b0r0=0,b0z0=0,b0n0=0,b0r1=0,b0z1=0,b0n1=0;
  float xi_r0=0,xi_z0=0,xi_n0=0,xi_r1=0,xi_z1=0,xi_n1=0;
  float b1r0=0,b1z0=0,b1n0=0,b1r1=0,b1z1=0,b1n1=0;
  const _Float16* xp = xg + (long)(ga ? gb * NT : 0) * NG + u0 + i0;
  v2h xr = {(_Float16)0, (_Float16)0}, xz = xr, xn2 = xr;
  if (ga) {
    const int ug = u0 + i0;
    h0p0 = hinit[gb * 512 + ug];              h0p1 = hinit[gb * 512 + ug + 1];
    h1p0 = hinit[NB * NH + gb * 512 + ug];    h1p1 = hinit[NB * NH + gb * 512 + ug + 1];
    b0r0 = bhh0[ug];        b0r1 = bhh0[ug + 1];
    b0z0 = bhh0[512 + ug];  b0z1 = bhh0[512 + ug + 1];
    b0n0 = bhh0[1024 + ug]; b0n1 = bhh0[1024 + ug + 1];
    xi_r0 = bih1[ug];        xi_r1 = bih1[ug + 1];
    xi_z0 = bih1[512 + ug];  xi_z1 = bih1[512 + ug + 1];
    xi_n0 = bih1[1024 + ug]; xi_n1 = bih1[1024 + ug + 1];
    b1r0 = bhh1[ug];        b1r1 = bhh1[ug + 1];
    b1z0 = bhh1[512 + ug];  b1z1 = bhh1[512 + ug + 1];
    b1n0 = bhh1[1024 + ug]; b1n1 = bhh1[1024 + ug + 1];
    xr  = *(const v2h*)xp;
    xz  = *(const v2h*)(xp + 512);
    xn2 = *(const v2h*)(xp + 1024);
  }

#pragma unroll 1
  for (int t = 0; t <= NT; ++t) {
    // prefetch xg0(t+1) behind the MFMA phase
    v2h pr = {(_Float16)0, (_Float16)0}, pz = pr, pn = pr;
    if (ga && t + 1 < NT) {
      const _Float16* q2 = xp + NG;
      pr = *(const v2h*)q2;
      pz = *(const v2h*)(q2 + 512);
      pn = *(const v2h*)(q2 + 1024);
    }
    // ---- MFMA phase: gh0, xg1 (share h0 B-frags), gh1 ----
    {
      v4f c00 = {0,0,0,0}, c01 = c00, cx0 = c00, cx1 = c00, c10 = c00, c11 = c00;
      const int kq = kh * 256 + q * 8;
      for (int ks = 0; ks < 8; ++ks) {
        const int k = kq + ks * 32;
        v8h b00 = *(const v8h*)&hs0[l15][k];
        v8h b01 = *(const v8h*)&hs0[9 + l15][k];
        v8h b10 = *(const v8h*)&hs1[l15][k];
        v8h b11 = *(const v8h*)&hs1[9 + l15][k];
        c00 = __builtin_amdgcn_mfma_f32_16x16x32_f16(a0[ks], b00, c00, 0, 0, 0);
        c01 = __builtin_amdgcn_mfma_f32_16x16x32_f16(a0[ks], b01, c01, 0, 0, 0);
        cx0 = __builtin_amdgcn_mfma_f32_16x16x32_f16(ax[ks], b00, cx0, 0, 0, 0);
        cx1 = __builtin_amdgcn_mfma_f32_16x16x32_f16(ax[ks], b01, cx1, 0, 0, 0);
        c10 = __builtin_amdgcn_mfma_f32_16x16x32_f16(a1[ks], b10, c10, 0, 0, 0);
        c11 = __builtin_amdgcn_mfma_f32_16x16x32_f16(a1[ks], b11, c11, 0, 0, 0);
      }
      const int row = mt * 16 + q * 4;
      for (int r = 0; r < 4; ++r) {
        g0[kh][row + r][l15]     = c00[r];
        g0[kh][row + r][9 + l15] = c01[r];
        gx[kh][row + r][l15]     = cx0[r];
        gx[kh][row + r][9 + l15] = cx1[r];
        g1[kh][row + r][l15]     = c10[r];
        g1[kh][row + r][9 + l15] = c11[r];
      }
    }
    __syncthreads();   // ghs ready; all hs reads done -> restage may overwrite hs
    // ---- gate phase ----
    if (ga) {
      const int di = gb * 256 + (u0 >> 1) + gj;
      if (t < NT) {
        // layer 0 step t: h0(t+1)
        float hr0 = g0[0][i0][gb]      + g0[1][i0][gb]      + b0r0;
        float hz0 = g0[0][16+i0][gb]   + g0[1][16+i0][gb]   + b0z0;
        float hn0 = g0[0][32+i0][gb]   + g0[1][32+i0][gb]   + b0n0;
        float hr1 = g0[0][i1][gb]      + g0[1][i1][gb]      + b0r1;
        float hz1 = g0[0][16+i1][gb]   + g0[1][16+i1][gb]   + b0z1;
        float hn1 = g0[0][32+i1][gb]   + g0[1][32+i1][gb]   + b0n1;
        float r0 = fsigmoid((float)xr[0] + hr0);
        float z0 = fsigmoid((float)xz[0] + hz0);
        float n0 = ftanh((float)xn2[0] + r0 * hn0);
        float r1 = fsigmoid((float)xr[1] + hr1);
        float z1 = fsigmoid((float)xz[1] + hz1);
        float n1 = ftanh((float)xn2[1] + r1 * hn1);
        float h0n0 = (1.f - z0) * n0 + z0 * h0p0;
        float h0n1 = (1.f - z1) * n1 + z1 * h0p1;
        h0p0 = h0n0; h0p1 = h0n1;
        _Float16 f0 = (_Float16)h0n0, f1 = (_Float16)h0n1;
        unsigned pk = (unsigned)(*(unsigned short*)&f0) | ((unsigned)(*(unsigned short*)&f1) << 16);
        __hip_atomic_store(&H0PK[(size_t)((t + 1) & 1) * 6400 + di],
                           ((ull)(unsigned)(t + 1) << 32) | (ull)pk,
                           __ATOMIC_RELAXED, __HIP_MEMORY_SCOPE_AGENT);
        if (t == NT - 1) { hfin0[gb * 512 + u0 + i0] = h0n0; hfin0[gb * 512 + u0 + i1] = h0n1; }
      }
      if (t >= 1) {
        // layer 1 step t-1: h1(t) from h1(t-1) and out0(t-1)=h0(t)=hs0
        float xrr0 = gx[0][i0][gb]    + gx[1][i0][gb]    + xi_r0;
        float xzz0 = gx[0][16+i0][gb] + gx[1][16+i0][gb] + xi_z0;
        float xnn0 = gx[0][32+i0][gb] + gx[1][32+i0][gb] + xi_n0;
        float xrr1 = gx[0][i1][gb]    + gx[1][i1][gb]    + xi_r1;
        float xzz1 = gx[0][16+i1][gb] + gx[1][16+i1][gb] + xi_z1;
        float xnn1 = gx[0][32+i1][gb] + gx[1][32+i1][gb] + xi_n1;
        float hr0 = g1[0][i0][gb]     + g1[1][i0][gb]    + b1r0;
        float hz0 = g1[0][16+i0][gb]  + g1[1][16+i0][gb] + b1z0;
        float hn0 = g1[0][32+i0][gb]  + g1[1][32+i0][gb] + b1n0;
        float hr1 = g1[0][i1][gb]     + g1[1][i1][gb]    + b1r1;
        float hz1 = g1[0][16+i1][gb]  + g1[1][16+i1][gb] + b1z1;
        float hn1 = g1[0][32+i1][gb]  + g1[1][32+i1][gb] + b1n1;
        float r0 = fsigmoid(xrr0 + hr0);
        float z0 = fsigmoid(xzz0 + hz0);
        float n0 = ftanh(xnn0 + r0 * hn0);
        float r1 = fsigmoid(xrr1 + hr1);
        float z1 = fsigmoid(xzz1 + hz1);
        float n1 = ftanh(xnn1 + r1 * hn1);
        float h1n0 = (1.f - z0) * n0 + z0 * h1p0;
        float h1n1 = (1.f - z1) * n1 + z1 * h1p1;
        h1p0 = h1n0; h1p1 = h1n1;
        if (t < NT) {
          _Float16 f0 = (_Float16)h1n0, f1 = (_Float16)h1n1;
          unsigned pk = (unsigned)(*(unsigned short*)&f0) | ((unsigned)(*(unsigned short*)&f1) << 16);
          __hip_atomic_store(&H1PK[(size_t)(t & 1) * 6400 + di],
                             ((ull)(unsigned)t << 32) | (ull)pk,
                             __ATOMIC_RELAXED, __HIP_MEMORY_SCOPE_AGENT);
        }
        if (t == NT) { hfin1[gb * 512 + u0 + i0] = h1n0; hfin1[gb * 512 + u0 + i1] = h1n1; }
      }
    }
    // ---- fused restage poll: h0 tag t+1 and h1 tag t, one sweep RT ----
    if (t < NT) {
      const ull* s0 = H0PK + (size_t)((t + 1) & 1) * 6400;
      const ull* s1 = H1PK + (size_t)(t & 1) * 6400;
      const unsigned w0 = (unsigned)(t + 1), w1 = (unsigned)t;
      unsigned ok0 = 0, ok1 = (t == 0) ? 0x1FFFFu : 0u;
#pragma unroll
      for (int k = 0; k < 17; ++k)
        if (tid + 384 * k >= 6400) { ok0 |= 1u << k; ok1 |= 1u << k; }
      while (ok0 != 0x1FFFFu || ok1 != 0x1FFFFu) {
        ull v0[17], v1[17];
#pragma unroll
        for (int k = 0; k < 17; ++k)
          if (!(ok0 & (1u << k)))
            v0[k] = __hip_atomic_load(&s0[tid + 384 * k], __ATOMIC_RELAXED, __HIP_MEMORY_SCOPE_AGENT);
#pragma unroll
        for (int k = 0; k < 17; ++k)
          if (!(ok1 & (1u << k)))
            v1[k] = __hip_atomic_load(&s1[tid + 384 * k], __ATOMIC_RELAXED, __HIP_MEMORY_SCOPE_AGENT);
#pragma unroll
        for (int k = 0; k < 17; ++k)
          if (!(ok0 & (1u << k)) && (unsigned)(v0[k] >> 32) == w0) {
            ok0 |= 1u << k;
            const int idx = tid + 384 * k;
            *(unsigned*)&hs0[idx >> 8][(idx & 255) * 2] = (unsigned)v0[k];
          }
#pragma unroll
        for (int k = 0; k < 17; ++k)
          if (!(ok1 & (1u << k)) && (unsigned)(v1[k] >> 32) == w1) {
            ok1 |= 1u << k;
            const int idx = tid + 384 * k;
            *(unsigned*)&hs1[idx >> 8][(idx & 255) * 2] = (unsigned)v1[k];
          }
      }
      __syncthreads();
    }
    xr = pr; xz = pz; xn2 = pn; xp += NG;
  }
}

// ---------------- final FC + sigmoid ----------------
__global__ __launch_bounds__(256) void k_final(
    const float* __restrict__ h1, const float* __restrict__ fcw,
    const float* __restrict__ fcb, float* __restrict__ sig)
{
  __shared__ float red[25][8];
  const int tid = threadIdx.x;
  const int b = tid >> 3, p = tid & 7;
  if (b < 25) {
    float s = 0.f;
    for (int k = p * 64; k < p * 64 + 64; ++k) s += h1[b * 512 + k] * fcw[k];
    red[b][p] = s;
  }
  __syncthreads();
  if (b < 25 && p == 0) {
    float d = red[b][0] + red[b][1] + red[b][2] + red[b][3]
            + red[b][4] + red[b][5] + red[b][6] + red[b][7];
    sig[b] = 1.f / (1.f + __expf(-(d + fcb[0])));
  }
}

extern "C" void kernel_launch(void* const* d_in, const int* in_sizes, int n_in,
                              void* d_out, int out_size, void* d_ws, size_t ws_size,
                              hipStream_t stream)
{
  (void)in_sizes; (void)n_in; (void)out_size;
  const int*   words  = (const int*)d_in[0];
  const float* hidden = (const float*)d_in[1];
  const float* emb    = (const float*)d_in[2];
  const float* w_ih0  = (const float*)d_in[3];
  const float* w_hh0  = (const float*)d_in[4];
  const float* b_ih0  = (const float*)d_in[5];
  const float* b_hh0  = (const float*)d_in[6];
  const float* w_ih1  = (const float*)d_in[7];
  const float* w_hh1  = (const float*)d_in[8];
  const float* b_ih1  = (const float*)d_in[9];
  const float* b_hh1  = (const float*)d_in[10];
  const float* fcw    = (const float*)d_in[11];
  const float* fcb    = (const float*)d_in[12];
  float* out = (float*)d_out;
  char* ws = (char*)d_ws;

  // ws: [0,256) pad | XG f16 46.08MB | H0PK 2x6400 ull | H1PK 2x6400 ull
  const size_t NEED = 256 + 46080000 + 2 * 102400;
  if (ws_size < NEED) return;

  _Float16* XG   = (_Float16*)(ws + 256);
  ull*      H0PK = (ull*)(ws + 256 + 46080000);
  ull*      H1PK = H0PK + 12800;

  dim3 gg(118, 12);
  k_gemm0<<<gg, dim3(256), 0, stream>>>(words, emb, w_ih0, b_ih0, XG);
  k_scan2<<<dim3(32), dim3(384), 0, stream>>>(XG, w_hh0, w_ih1, w_hh1,
                                              b_hh0, b_ih1, b_hh1, hidden,
                                              H0PK, H1PK,
                                              out + 25, out + 25 + NB * NH);
  k_final<<<dim3(1), dim3(256), 0, stream>>>(out + 25 + NB * NH, fcw, fcb, out);
}

// Round 5
// 4729.112 us; speedup vs baseline: 1.0827x; 1.0827x over previous
//
#include <hip/hip_runtime.h>

#define NV 100000
#define ND 300
#define NH 512
#define NB 25
#define NT 600
#define NM 15000   // NB*NT
#define NG 1536    // 3*NH

typedef _Float16 v8h __attribute__((ext_vector_type(8)));
typedef _Float16 v4h __attribute__((ext_vector_type(4)));
typedef _Float16 v2h __attribute__((ext_vector_type(2)));
typedef float    v4f __attribute__((ext_vector_type(4)));
typedef unsigned long long ull;

static __device__ __forceinline__ float fsigmoid(float x) {
  return __builtin_amdgcn_rcpf(1.f + __expf(-x));
}
static __device__ __forceinline__ float ftanh(float x) {
  return 1.f - 2.f * __builtin_amdgcn_rcpf(1.f + __expf(2.f * x));
}

// ---------------- GEMM: Cxg[m][n] = emb[words[m]]·w_ih0[n] + b_ih0[n], f16 out ----
__global__ __launch_bounds__(256) void k_gemm0(
    const int* __restrict__ words, const float* __restrict__ emb,
    const float* __restrict__ Bw, const float* __restrict__ bias,
    _Float16* __restrict__ Cxg)
{
  constexpr int K = ND;
  constexpr int NKT = (K + 31) / 32;
  __shared__ _Float16 As[128][40];
  __shared__ _Float16 Bh[128][40];
  __shared__ _Float16 Bl[128][40];
  const int tid = threadIdx.x;
  const int m0 = blockIdx.x * 128, n0 = blockIdx.y * 128;
  const int w = tid >> 6, l = tid & 63;
  const int wm = w >> 1, wn = w & 1;
  const int l15 = l & 15, q = l >> 4;

  v4f accH[4][4], accL[4][4];
  for (int a = 0; a < 4; ++a)
    for (int b = 0; b < 4; ++b) {
      v4f z = {0.f, 0.f, 0.f, 0.f};
      accH[a][b] = z; accL[a][b] = z;
    }

#pragma unroll 1
  for (int kt = 0; kt < NKT; ++kt) {
    const int kb = kt * 32;
    for (int jj = 0; jj < 4; ++jj) {
      const int F = tid + 256 * jj;
      const int row = F >> 3;
      const int kl = (F & 7) * 4;
      {
        const int m = m0 + row;
        float x0 = 0.f, x1 = 0.f, x2 = 0.f, x3 = 0.f;
        if (m < NM) {
          const int word = words[m];
          const float* ap = emb + (long)word * ND + kb + kl;
          if (kb + kl + 3 < K) {
            float4 v = *(const float4*)ap;
            x0 = v.x; x1 = v.y; x2 = v.z; x3 = v.w;
          } else {
            if (kb + kl + 0 < K) x0 = ap[0];
            if (kb + kl + 1 < K) x1 = ap[1];
            if (kb + kl + 2 < K) x2 = ap[2];
            if (kb + kl + 3 < K) x3 = ap[3];
          }
        }
        v4h hv; hv[0]=(_Float16)x0; hv[1]=(_Float16)x1; hv[2]=(_Float16)x2; hv[3]=(_Float16)x3;
        *(v4h*)&As[row][kl] = hv;
      }
      {
        const int n = n0 + row;
        const float* bp = Bw + (long)n * K + kb + kl;
        float x[4] = {0.f, 0.f, 0.f, 0.f};
        if (kb + kl + 3 < K) {
          float4 v = *(const float4*)bp;
          x[0] = v.x; x[1] = v.y; x[2] = v.z; x[3] = v.w;
        } else {
          for (int c = 0; c < 4; ++c) if (kb + kl + c < K) x[c] = bp[c];
        }
        v4h bh, bl;
        for (int c = 0; c < 4; ++c) {
          _Float16 hi = (_Float16)x[c];
          bh[c] = hi;
          bl[c] = (_Float16)((x[c] - (float)hi) * 1024.f);
        }
        *(v4h*)&Bh[row][kl] = bh;
        *(v4h*)&Bl[row][kl] = bl;
      }
    }
    __syncthreads();
    v8h af[4];
    for (int mt = 0; mt < 4; ++mt) {
      const int r = wm * 64 + mt * 16 + l15;
      af[mt] = *(const v8h*)&As[r][q * 8];
    }
    for (int nt = 0; nt < 4; ++nt) {
      const int r = wn * 64 + nt * 16 + l15;
      v8h bh = *(const v8h*)&Bh[r][q * 8];
      v8h bl = *(const v8h*)&Bl[r][q * 8];
      for (int mt = 0; mt < 4; ++mt) {
        accH[mt][nt] = __builtin_amdgcn_mfma_f32_16x16x32_f16(af[mt], bh, accH[mt][nt], 0, 0, 0);
        accL[mt][nt] = __builtin_amdgcn_mfma_f32_16x16x32_f16(af[mt], bl, accL[mt][nt], 0, 0, 0);
      }
    }
    __syncthreads();
  }
  for (int nt = 0; nt < 4; ++nt) {
    const int n = n0 + wn * 64 + nt * 16 + l15;
    const float bv = bias[n];
    for (int mt = 0; mt < 4; ++mt) {
      for (int r = 0; r < 4; ++r) {
        const int m = m0 + wm * 64 + mt * 16 + q * 4 + r;
        if (m < NM) {
          const float cv = accH[mt][nt][r] + accL[mt][nt][r] * (1.f / 1024.f) + bv;
          Cxg[(long)m * NG + n] = (_Float16)cv;
        }
      }
    }
  }
}

// ---------------- fused 2-layer persistent GRU scan ----------------
// 32 blocks x 384 thr = 6 waves = (mt in 0..2) x (kh in 0..1 K-halves).
// Writers: device-scope tagged 8B atomic stores (L2-bypassing, fire-and-forget).
// Readers: ORDINARY dwordx4 loads of tagged slots, preceded per sweep by an
// agent-acquire fence (buffer_inv) -> pipelined 1-RT sweeps, no per-load
// atomic serialization. Tag-in-payload makes retries safe; parity-2 buffers
// are race-free by the lockstep argument (a tag t+3 store requires every
// block to have consumed tag t+1 first).
__global__ __launch_bounds__(384) void k_scan2(
    const _Float16* __restrict__ xg,    // [NM][NG] f16, includes b_ih0
    const float* __restrict__ whh0,     // [NG][NH]
    const float* __restrict__ wih1,     // [NG][NH]
    const float* __restrict__ whh1,     // [NG][NH]
    const float* __restrict__ bhh0,     // [NG]
    const float* __restrict__ bih1,     // [NG]
    const float* __restrict__ bhh1,     // [NG]
    const float* __restrict__ hinit,    // [2][NB][NH]
    ull* __restrict__ H0PK,             // [2][6400] tagged h0 pairs
    ull* __restrict__ H1PK,             // [2][6400] tagged h1 pairs
    float* __restrict__ hfin0,          // d_out h0 slice
    float* __restrict__ hfin1)          // d_out h1 slice
{
  __shared__ __align__(16) _Float16 hs0[NB][520];
  __shared__ __align__(16) _Float16 hs1[NB][520];
  __shared__ float g0[2][48][28];   // gh0 partials per K-half
  __shared__ float gx[2][48][28];   // xg1 partials
  __shared__ float g1[2][48][28];   // gh1 partials
  const int tid = threadIdx.x;
  const int u0 = blockIdx.x * 16;
  const int w = tid >> 6, l = tid & 63;
  const int mt = w % 3, kh = w / 3;
  const int l15 = l & 15, q = l >> 4;

  // ---- W fragments -> registers (single f16) ----
  v8h a0[8], ax[8], a1[8];
  {
    const long base = (long)(mt * 512 + u0 + l15) * 512 + kh * 256 + q * 8;
    for (int ks = 0; ks < 8; ++ks) {
      float4 v0, v1;
      v8h h;
      v0 = *(const float4*)(whh0 + base + ks * 32);
      v1 = *(const float4*)(whh0 + base + ks * 32 + 4);
      h[0]=(_Float16)v0.x; h[1]=(_Float16)v0.y; h[2]=(_Float16)v0.z; h[3]=(_Float16)v0.w;
      h[4]=(_Float16)v1.x; h[5]=(_Float16)v1.y; h[6]=(_Float16)v1.z; h[7]=(_Float16)v1.w;
      a0[ks] = h;
      v0 = *(const float4*)(wih1 + base + ks * 32);
      v1 = *(const float4*)(wih1 + base + ks * 32 + 4);
      h[0]=(_Float16)v0.x; h[1]=(_Float16)v0.y; h[2]=(_Float16)v0.z; h[3]=(_Float16)v0.w;
      h[4]=(_Float16)v1.x; h[5]=(_Float16)v1.y; h[6]=(_Float16)v1.z; h[7]=(_Float16)v1.w;
      ax[ks] = h;
      v0 = *(const float4*)(whh1 + base + ks * 32);
      v1 = *(const float4*)(whh1 + base + ks * 32 + 4);
      h[0]=(_Float16)v0.x; h[1]=(_Float16)v0.y; h[2]=(_Float16)v0.z; h[3]=(_Float16)v0.w;
      h[4]=(_Float16)v1.x; h[5]=(_Float16)v1.y; h[6]=(_Float16)v1.z; h[7]=(_Float16)v1.w;
      a1[ks] = h;
    }
  }
  // ---- initial h stage ----
  for (int idx = tid; idx < NB * NH; idx += 384) {
    hs0[idx >> 9][idx & 511] = (_Float16)hinit[idx];
    hs1[idx >> 9][idx & 511] = (_Float16)hinit[NB * NH + idx];
  }
  __syncthreads();

  const bool ga = (tid < 200);         // (batch gb 0..24) x (gj 0..7), 2 units each
  const int gb = tid >> 3, gj = tid & 7;
  const int i0 = 2 * gj, i1 = i0 + 1;

  // exact fp32 recurrent state (thread-private: the same thread updates it)
  float h0p0 = 0.f, h0p1 = 0.f, h1p0 = 0.f, h1p1 = 0.f;
  float b0r0=0,b0z0=0,b0n0=0,b0r1=0,b0z1=0,b0n1=0;
  float xi_r0=0,xi_z0=0,xi_n0=0,xi_r1=0,xi_z1=0,xi_n1=0;
  float b1r0=0,b1z0=0,b1n0=0,b1r1=0,b1z1=0,b1n1=0;
  const _Float16* xp = xg + (long)(ga ? gb * NT : 0) * NG + u0 + i0;
  v2h xr = {(_Float16)0, (_Float16)0}, xz = xr, xn2 = xr;
  if (ga) {
    const int ug = u0 + i0;
    h0p0 = hinit[gb * 512 + ug];              h0p1 = hinit[gb * 512 + ug + 1];
    h1p0 = hinit[NB * NH + gb * 512 + ug];    h1p1 = hinit[NB * NH + gb * 512 + ug + 1];
    b0r0 = bhh0[ug];        b0r1 = bhh0[ug + 1];
    b0z0 = bhh0[512 + ug];  b0z1 = bhh0[512 + ug + 1];
    b0n0 = bhh0[1024 + ug]; b0n1 = bhh0[1024 + ug + 1];
    xi_r0 = bih1[ug];        xi_r1 = bih1[ug + 1];
    xi_z0 = bih1[512 + ug];  xi_z1 = bih1[512 + ug + 1];
    xi_n0 = bih1[1024 + ug]; xi_n1 = bih1[1024 + ug + 1];
    b1r0 = bhh1[ug];        b1r1 = bhh1[ug + 1];
    b1z0 = bhh1[512 + ug];  b1z1 = bhh1[512 + ug + 1];
    b1n0 = bhh1[1024 + ug]; b1n1 = bhh1[1024 + ug + 1];
    xr  = *(const v2h*)xp;
    xz  = *(const v2h*)(xp + 512);
    xn2 = *(const v2h*)(xp + 1024);
  }

#pragma unroll 1
  for (int t = 0; t <= NT; ++t) {
    // prefetch xg0(t+1) behind the MFMA phase
    v2h pr = {(_Float16)0, (_Float16)0}, pz = pr, pn = pr;
    if (ga && t + 1 < NT) {
      const _Float16* q2 = xp + NG;
      pr = *(const v2h*)q2;
      pz = *(const v2h*)(q2 + 512);
      pn = *(const v2h*)(q2 + 1024);
    }
    // ---- MFMA phase: gh0, xg1 (share h0 B-frags), gh1 ----
    {
      v4f c00 = {0,0,0,0}, c01 = c00, cx0 = c00, cx1 = c00, c10 = c00, c11 = c00;
      const int kq = kh * 256 + q * 8;
      for (int ks = 0; ks < 8; ++ks) {
        const int k = kq + ks * 32;
        v8h b00 = *(const v8h*)&hs0[l15][k];
        v8h b01 = *(const v8h*)&hs0[9 + l15][k];
        v8h b10 = *(const v8h*)&hs1[l15][k];
        v8h b11 = *(const v8h*)&hs1[9 + l15][k];
        c00 = __builtin_amdgcn_mfma_f32_16x16x32_f16(a0[ks], b00, c00, 0, 0, 0);
        c01 = __builtin_amdgcn_mfma_f32_16x16x32_f16(a0[ks], b01, c01, 0, 0, 0);
        cx0 = __builtin_amdgcn_mfma_f32_16x16x32_f16(ax[ks], b00, cx0, 0, 0, 0);
        cx1 = __builtin_amdgcn_mfma_f32_16x16x32_f16(ax[ks], b01, cx1, 0, 0, 0);
        c10 = __builtin_amdgcn_mfma_f32_16x16x32_f16(a1[ks], b10, c10, 0, 0, 0);
        c11 = __builtin_amdgcn_mfma_f32_16x16x32_f16(a1[ks], b11, c11, 0, 0, 0);
      }
      const int row = mt * 16 + q * 4;
      for (int r = 0; r < 4; ++r) {
        g0[kh][row + r][l15]     = c00[r];
        g0[kh][row + r][9 + l15] = c01[r];
        gx[kh][row + r][l15]     = cx0[r];
        gx[kh][row + r][9 + l15] = cx1[r];
        g1[kh][row + r][l15]     = c10[r];
        g1[kh][row + r][9 + l15] = c11[r];
      }
    }
    __syncthreads();   // ghs ready; all hs reads done -> restage may overwrite hs
    // ---- gate phase ----
    if (ga) {
      const int di = gb * 256 + (u0 >> 1) + gj;
      if (t < NT) {
        // layer 0 step t: h0(t+1)
        float hr0 = g0[0][i0][gb]      + g0[1][i0][gb]      + b0r0;
        float hz0 = g0[0][16+i0][gb]   + g0[1][16+i0][gb]   + b0z0;
        float hn0 = g0[0][32+i0][gb]   + g0[1][32+i0][gb]   + b0n0;
        float hr1 = g0[0][i1][gb]      + g0[1][i1][gb]      + b0r1;
        float hz1 = g0[0][16+i1][gb]   + g0[1][16+i1][gb]   + b0z1;
        float hn1 = g0[0][32+i1][gb]   + g0[1][32+i1][gb]   + b0n1;
        float r0 = fsigmoid((float)xr[0] + hr0);
        float z0 = fsigmoid((float)xz[0] + hz0);
        float n0 = ftanh((float)xn2[0] + r0 * hn0);
        float r1 = fsigmoid((float)xr[1] + hr1);
        float z1 = fsigmoid((float)xz[1] + hz1);
        float n1 = ftanh((float)xn2[1] + r1 * hn1);
        float h0n0 = (1.f - z0) * n0 + z0 * h0p0;
        float h0n1 = (1.f - z1) * n1 + z1 * h0p1;
        h0p0 = h0n0; h0p1 = h0n1;
        _Float16 f0 = (_Float16)h0n0, f1 = (_Float16)h0n1;
        unsigned pk = (unsigned)(*(unsigned short*)&f0) | ((unsigned)(*(unsigned short*)&f1) << 16);
        __hip_atomic_store(&H0PK[(size_t)((t + 1) & 1) * 6400 + di],
                           ((ull)(unsigned)(t + 1) << 32) | (ull)pk,
                           __ATOMIC_RELAXED, __HIP_MEMORY_SCOPE_AGENT);
        if (t == NT - 1) { hfin0[gb * 512 + u0 + i0] = h0n0; hfin0[gb * 512 + u0 + i1] = h0n1; }
      }
      if (t >= 1) {
        // layer 1 step t-1: h1(t) from h1(t-1) and out0(t-1)=h0(t)=hs0
        float xrr0 = gx[0][i0][gb]    + gx[1][i0][gb]    + xi_r0;
        float xzz0 = gx[0][16+i0][gb] + gx[1][16+i0][gb] + xi_z0;
        float xnn0 = gx[0][32+i0][gb] + gx[1][32+i0][gb] + xi_n0;
        float xrr1 = gx[0][i1][gb]    + gx[1][i1][gb]    + xi_r1;
        float xzz1 = gx[0][16+i1][gb] + gx[1][16+i1][gb] + xi_z1;
        float xnn1 = gx[0][32+i1][gb] + gx[1][32+i1][gb] + xi_n1;
        float hr0 = g1[0][i0][gb]     + g1[1][i0][gb]    + b1r0;
        float hz0 = g1[0][16+i0][gb]  + g1[1][16+i0][gb] + b1z0;
        float hn0 = g1[0][32+i0][gb]  + g1[1][32+i0][gb] + b1n0;
        float hr1 = g1[0][i1][gb]     + g1[1][i1][gb]    + b1r1;
        float hz1 = g1[0][16+i1][gb]  + g1[1][16+i1][gb] + b1z1;
        float hn1 = g1[0][32+i1][gb]  + g1[1][32+i1][gb] + b1n1;
        float r0 = fsigmoid(xrr0 + hr0);
        float z0 = fsigmoid(xzz0 + hz0);
        float n0 = ftanh(xnn0 + r0 * hn0);
        float r1 = fsigmoid(xrr1 + hr1);
        float z1 = fsigmoid(xzz1 + hz1);
        float n1 = ftanh(xnn1 + r1 * hn1);
        float h1n0 = (1.f - z0) * n0 + z0 * h1p0;
        float h1n1 = (1.f - z1) * n1 + z1 * h1p1;
        h1p0 = h1n0; h1p1 = h1n1;
        if (t < NT) {
          _Float16 f0 = (_Float16)h1n0, f1 = (_Float16)h1n1;
          unsigned pk = (unsigned)(*(unsigned short*)&f0) | ((unsigned)(*(unsigned short*)&f1) << 16);
          __hip_atomic_store(&H1PK[(size_t)(t & 1) * 6400 + di],
                             ((ull)(unsigned)t << 32) | (ull)pk,
                             __ATOMIC_RELAXED, __HIP_MEMORY_SCOPE_AGENT);
        }
        if (t == NT) { hfin1[gb * 512 + u0 + i0] = h1n0; hfin1[gb * 512 + u0 + i1] = h1n1; }
      }
    }
    // ---- restage poll: ordinary pipelined 16B loads + per-sweep acquire fence ----
    if (t < NT) {
      const ulonglong2* p0 = (const ulonglong2*)(H0PK + (size_t)((t + 1) & 1) * 6400);
      const ulonglong2* p1 = (const ulonglong2*)(H1PK + (size_t)(t & 1) * 6400);
      const unsigned w0 = (unsigned)(t + 1), w1 = (unsigned)t;
      const unsigned FULL = 0x3FFFFu;       // 9 pairs x 2 slots
      unsigned ok0 = 0, ok1 = (t == 0) ? FULL : 0u;
#pragma unroll
      for (int k = 0; k < 9; ++k)
        if (tid + 384 * k >= 3200) { ok0 |= 3u << (2 * k); ok1 |= 3u << (2 * k); }
      while (ok0 != FULL || ok1 != FULL) {
        __builtin_amdgcn_fence(__ATOMIC_ACQUIRE, "agent");   // waitcnt + buffer_inv
        ulonglong2 v0[9], v1[9];
#pragma unroll
        for (int k = 0; k < 9; ++k)
          if (((ok0 >> (2 * k)) & 3u) != 3u) v0[k] = p0[tid + 384 * k];
#pragma unroll
        for (int k = 0; k < 9; ++k)
          if (((ok1 >> (2 * k)) & 3u) != 3u) v1[k] = p1[tid + 384 * k];
#pragma unroll
        for (int k = 0; k < 9; ++k) {
          const int base = 2 * (tid + 384 * k);
#pragma unroll
          for (int j = 0; j < 2; ++j) {
            const unsigned bit = 1u << (2 * k + j);
            {
              const ull vv = j ? v0[k].y : v0[k].x;
              if (!(ok0 & bit) && (unsigned)(vv >> 32) == w0) {
                ok0 |= bit;
                const int idx = base + j;
                *(unsigned*)&hs0[idx >> 8][(idx & 255) * 2] = (unsigned)vv;
              }
            }
            {
              const ull vv = j ? v1[k].y : v1[k].x;
              if (!(ok1 & bit) && (unsigned)(vv >> 32) == w1) {
                ok1 |= bit;
                const int idx = base + j;
                *(unsigned*)&hs1[idx >> 8][(idx & 255) * 2] = (unsigned)vv;
              }
            }
          }
        }
      }
      __syncthreads();
    }
    xr = pr; xz = pz; xn2 = pn; xp += NG;
  }
}

// ---------------- final FC + sigmoid ----------------
__global__ __launch_bounds__(256) void k_final(
    const float* __restrict__ h1, const float* __restrict__ fcw,
    const float* __restrict__ fcb, float* __restrict__ sig)
{
  __shared__ float red[25][8];
  const int tid = threadIdx.x;
  const int b = tid >> 3, p = tid & 7;
  if (b < 25) {
    float s = 0.f;
    for (int k = p * 64; k < p * 64 + 64; ++k) s += h1[b * 512 + k] * fcw[k];
    red[b][p] = s;
  }
  __syncthreads();
  if (b < 25 && p == 0) {
    float d = red[b][0] + red[b][1] + red[b][2] + red[b][3]
            + red[b][4] + red[b][5] + red[b][6] + red[b][7];
    sig[b] = 1.f / (1.f + __expf(-(d + fcb[0])));
  }
}

extern "C" void kernel_launch(void* const* d_in, const int* in_sizes, int n_in,
                              void* d_out, int out_size, void* d_ws, size_t ws_size,
                              hipStream_t stream)
{
  (void)in_sizes; (void)n_in; (void)out_size;
  const int*   words  = (const int*)d_in[0];
  const float* hidden = (const float*)d_in[1];
  const float* emb    = (const float*)d_in[2];
  const float* w_ih0  = (const float*)d_in[3];
  const float* w_hh0  = (const float*)d_in[4];
  const float* b_ih0  = (const float*)d_in[5];
  const float* b_hh0  = (const float*)d_in[6];
  const float* w_ih1  = (const float*)d_in[7];
  const float* w_hh1  = (const float*)d_in[8];
  const float* b_ih1  = (const float*)d_in[9];
  const float* b_hh1  = (const float*)d_in[10];
  const float* fcw    = (const float*)d_in[11];
  const float* fcb    = (const float*)d_in[12];
  float* out = (float*)d_out;
  char* ws = (char*)d_ws;

  // ws: [0,256) pad | XG f16 46.08MB | H0PK 2x6400 ull | H1PK 2x6400 ull
  const size_t NEED = 256 + 46080000 + 2 * 102400;
  if (ws_size < NEED) return;

  _Float16* XG   = (_Float16*)(ws + 256);
  ull*      H0PK = (ull*)(ws + 256 + 46080000);
  ull*      H1PK = H0PK + 12800;

  dim3 gg(118, 12);
  k_gemm0<<<gg, dim3(256), 0, stream>>>(words, emb, w_ih0, b_ih0, XG);
  k_scan2<<<dim3(32), dim3(384), 0, stream>>>(XG, w_hh0, w_ih1, w_hh1,
                                              b_hh0, b_ih1, b_hh1, hidden,
                                              H0PK, H1PK,
                                              out + 25, out + 25 + NB * NH);
  k_final<<<dim3(1), dim3(256), 0, stream>>>(out + 25 + NB * NH, fcw, fcb, out);
}